// Round 1
// baseline (393.921 us; speedup 1.0000x reference)
//
#include <hip/hip_runtime.h>

// Graph WaveNet GCN on gfx950, bf16 MFMA pipeline.
// out[n,o,w,l] = b[o] + sum_{blk,c} W[o,blk*32+c] * H_blk[n,c,w,l]
//   H_0 = x,  H_{1+p} = x @ P_p over v,  P = [A0, A0^2, A1, A1^2, A2, A2^2]
//
// ws layout (bytes):
//   XT   @ 0          : Xt[(b*32+c)*13+l][v] bf16, 26624x512   (= block 0 of H)
//   Y    @ 27262976   : Y[p][m][w] bf16, 6 x 26624x512          (blocks 1..6)
//   BT   @ 190840832  : Bt[p][w][v] bf16  (P_p^T, NT-GEMM B operand), 6 x 512x512
//   ABF  @ 193986560  : A_s bf16 row-major (B operand for squaring GEMM), 3 x 512x512
//   WBF  @ 195559424  : W bf16 [64][224]
// total 195,588,096 B

typedef unsigned short u16;
typedef unsigned int   u32;
typedef __bf16 bf16x8 __attribute__((ext_vector_type(8)));
typedef float  f32x4  __attribute__((ext_vector_type(4)));

#define DEVI static __device__ __forceinline__

#define NB   64
#define NC   32
#define NV   512
#define NL   13
#define CO   64
#define CCAT 224
#define MROWS 26624          // NB*NC*NL, = 208*128
#define SZA   262144L        // 512*512
#define MSZ   (26624L * 512L)

DEVI u16 f2bf(float f) {
  union { float f; u32 u; } v; v.f = f;
  u32 u = v.u;
  return (u16)((u + 0x7fffu + ((u >> 16) & 1u)) >> 16);  // RNE
}

DEVI void gl2lds16(const void* g, void* l) {
  // async global->LDS, 16B/lane; LDS dest = wave-uniform base + lane*16
  __builtin_amdgcn_global_load_lds((__attribute__((address_space(1))) void*)g,
                                   (__attribute__((address_space(3))) void*)l, 16, 0, 0);
}

// ---------------------------------------------------------------- prep: supports
// For each s: Bt[2s] = A_s^T (bf16), ABF[s] = A_s (bf16). Tiles 32x32 via LDS.
__global__ __launch_bounds__(256) void prep_A(const float* __restrict__ A0,
                                              const float* __restrict__ A1,
                                              const float* __restrict__ A2,
                                              u16* __restrict__ BT,
                                              u16* __restrict__ ABF) {
  const int s = blockIdx.z;
  const float* A = (s == 0) ? A0 : ((s == 1) ? A1 : A2);
  u16* abf = ABF + (long)s * SZA;
  u16* bt  = BT + (long)(2 * s) * SZA;
  __shared__ float t[32][33];
  const int v0 = blockIdx.x * 32, w0 = blockIdx.y * 32;
  const int tid = threadIdx.x;
  for (int i = tid; i < 1024; i += 256) {
    const int r = i >> 5, c = i & 31;
    const float val = A[(long)(v0 + r) * 512 + w0 + c];
    t[r][c] = val;
    abf[(long)(v0 + r) * 512 + w0 + c] = f2bf(val);
  }
  __syncthreads();
  for (int i = tid; i < 1024; i += 256) {
    const int r = i >> 5, c = i & 31;  // r: w-local, c: v-local
    bt[(long)(w0 + r) * 512 + v0 + c] = f2bf(t[c][r]);
  }
}

// ---------------------------------------------------------------- prep: W -> bf16
__global__ __launch_bounds__(256) void prep_W(const float* __restrict__ W,
                                              u16* __restrict__ WBF) {
  const int i = blockIdx.x * 256 + threadIdx.x;  // grid 56*256 == 14336 exactly
  WBF[i] = f2bf(W[i]);
}

// ---------------------------------------------------------------- transpose x
// x[b][c][v][l] fp32 -> Xt[(b*32+c)*13+l][v] bf16. One block per (b,c).
__global__ __launch_bounds__(256) void transpose_x(const float* __restrict__ x,
                                                   u16* __restrict__ XT) {
  __shared__ __align__(16) float tile[NV * NL];  // 26.6 KB
  const int bc = blockIdx.x;
  const float4* src4 = (const float4*)(x + (long)bc * (NV * NL));
  float4* t4 = (float4*)tile;
  for (int i = threadIdx.x; i < (NV * NL) / 4; i += 256) t4[i] = src4[i];
  __syncthreads();
  u16* dst = XT + (long)bc * (NL * NV);
  for (int j = threadIdx.x; j < NL * NV; j += 256) {
    const int l = j >> 9, v = j & 511;     // j = l*512 + v
    dst[j] = f2bf(tile[v * NL + l]);       // stride-13 LDS read: conflict-free
  }
}

// ---------------------------------------------------------------- NT GEMM, K=512
// C[m][n] = sum_k A[m][k]*B[n][k]; all leading dims 512, K = 512, bf16 in/out.
// grid: (nTiles, mTiles, z); per-z pointer strides passed in.
// m97 structure: 128x128 tile, 4 waves (2x2 of 64x64), global_load_lds width 16.
__global__ __launch_bounds__(256) void gemm512(const u16* __restrict__ Ag,
                                               const u16* __restrict__ Bg,
                                               u16* __restrict__ Cg,
                                               long aZ, long bZ, long cZ) {
  __shared__ u16 As[128 * 32];
  __shared__ u16 Bs[128 * 32];
  const int p = blockIdx.z;
  const u16* A = Ag + (long)p * aZ;
  const u16* B = Bg + (long)p * bZ;
  u16*       C = Cg + (long)p * cZ;
  const int m0 = blockIdx.y * 128, n0 = blockIdx.x * 128;
  const int tid = threadIdx.x;
  const int lane = tid & 63, wid = tid >> 6;
  const int wm = wid >> 1, wn = wid & 1;
  const int lr = lane & 15, lq = lane >> 4;
  const int srow = lane >> 2, skq = lane & 3;   // staging: 16 rows/inst, 4 lanes/row

  f32x4 acc[4][4] = {};

  for (int kt = 0; kt < 16; ++kt) {
    const int k0 = kt * 32;
    __syncthreads();
#pragma unroll
    for (int j = 0; j < 2; ++j) {
      const int rb = wid * 32 + j * 16;
      gl2lds16(A + (long)(m0 + rb + srow) * 512 + (k0 + skq * 8), &As[rb * 32]);
      gl2lds16(B + (long)(n0 + rb + srow) * 512 + (k0 + skq * 8), &Bs[rb * 32]);
    }
    __syncthreads();
    bf16x8 af[4], bv[4];
#pragma unroll
    for (int t = 0; t < 4; ++t) {
      af[t] = *(const bf16x8*)&As[(wm * 64 + t * 16 + lr) * 32 + lq * 8];
      bv[t] = *(const bf16x8*)&Bs[(wn * 64 + t * 16 + lr) * 32 + lq * 8];
    }
#pragma unroll
    for (int i = 0; i < 4; ++i)
#pragma unroll
      for (int j = 0; j < 4; ++j)
        acc[i][j] = __builtin_amdgcn_mfma_f32_16x16x32_bf16(af[i], bv[j], acc[i][j], 0, 0, 0);
  }
#pragma unroll
  for (int i = 0; i < 4; ++i) {
    const int mr = m0 + wm * 64 + i * 16 + lq * 4;   // C/D row = quad*4 + reg
#pragma unroll
    for (int j = 0; j < 4; ++j) {
      const int nc = n0 + wn * 64 + j * 16 + lr;     // C/D col = lane&15
#pragma unroll
      for (int r = 0; r < 4; ++r)
        C[(long)(mr + r) * 512 + nc] = f2bf(acc[i][j][r]);
    }
  }
}

// ---------------------------------------------------------------- channel projection
// Per block: n = blockIdx.y, w-chunk = blockIdx.x (32 w's).
// out tile [64 o][32 w][16 lp(pad)] = W[64x224] @ H[224 x 512cols], K-chunk = 32 (one blk).
// H staged to LDS transposed: Hs[j' = w*16+lp][cc(32)], XOR-swizzled 16B chunks by (w&3).
__global__ __launch_bounds__(256) void proj_out(const u16* __restrict__ Yall, // [7][26624][512]
                                                const u16* __restrict__ WBF,  // [64][224]
                                                const float* __restrict__ bias,
                                                float* __restrict__ out) {
  __shared__ u16 Hs[512 * 32];  // 32 KB
  const int n = blockIdx.y, wch = blockIdx.x;
  const int tid = threadIdx.x;
  const int lane = tid & 63, wid = tid >> 6;
  const int lr = lane & 15, lq = lane >> 4;
  const int wq = tid & 15, cp = tid >> 4;    // staging: wq -> w pair, cp -> c pair

  f32x4 acc[32] = {};
  float bia[4];
#pragma unroll
  for (int r = 0; r < 4; ++r) bia[r] = bias[wid * 16 + lq * 4 + r];

  for (int blk = 0; blk < 7; ++blk) {
    const u16* Y = Yall + (long)blk * MSZ;
    __syncthreads();
    // stage: thread covers c in {2cp,2cp+1}, w_local in {2wq,2wq+1}, all 13 lp
    const long rbase = ((long)(n * NC + cp * 2) * NL) * 512 + wch * 32 + wq * 2;
#pragma unroll
    for (int lp = 0; lp < NL; ++lp) {
      const u32 a = *(const u32*)(Y + rbase + (long)lp * 512);            // c0 @ (w0,w0+1)
      const u32 b = *(const u32*)(Y + rbase + (long)lp * 512 + NL * 512); // c0+1 @ (w0,w0+1)
      const u32 pack0 = (a & 0xffffu) | (b << 16);       // (c0,c0+1) @ w0
      const u32 pack1 = (a >> 16) | (b & 0xffff0000u);   // (c0,c0+1) @ w0+1
      const int w0_ = wq * 2, w1_ = w0_ + 1;
      const int g = cp >> 2, wic = cp & 3;
      *(u32*)&Hs[(w0_ * 16 + lp) * 32 + ((g ^ (w0_ & 3)) * 8) + wic * 2] = pack0;
      *(u32*)&Hs[(w1_ * 16 + lp) * 32 + ((g ^ (w1_ & 3)) * 8) + wic * 2] = pack1;
    }
    __syncthreads();
    // A-frag straight from global (W is 28 KB, L1-resident)
    const bf16x8 af = *(const bf16x8*)&WBF[(wid * 16 + lr) * CCAT + blk * 32 + lq * 8];
#pragma unroll
    for (int t = 0; t < 32; ++t) {  // tile t <-> w_local = t, columns = lp 0..15
      const bf16x8 bv = *(const bf16x8*)&Hs[(t * 16 + lr) * 32 + ((lq ^ (t & 3)) * 8)];
      acc[t] = __builtin_amdgcn_mfma_f32_16x16x32_bf16(af, bv, acc[t], 0, 0, 0);
    }
  }
  if (lr < NL) {  // columns lp >= 13 are padding
#pragma unroll
    for (int t = 0; t < 32; ++t) {
      const int w = wch * 32 + t;
      const long base = (((long)n * CO + wid * 16 + lq * 4) * 512 + w) * NL + lr;
#pragma unroll
      for (int r = 0; r < 4; ++r)
        out[base + (long)r * (512 * NL)] = acc[t][r] + bia[r];
    }
  }
}

extern "C" void kernel_launch(void* const* d_in, const int* in_sizes, int n_in,
                              void* d_out, int out_size, void* d_ws, size_t ws_size,
                              hipStream_t stream) {
  const float* x  = (const float*)d_in[0];
  const float* s0 = (const float*)d_in[1];
  const float* s1 = (const float*)d_in[2];
  const float* s2 = (const float*)d_in[3];
  const float* W  = (const float*)d_in[4];
  const float* b  = (const float*)d_in[5];
  float* out = (float*)d_out;

  char* ws = (char*)d_ws;
  u16* XT  = (u16*)(ws);                 // also serves as Yall block 0
  u16* Y   = (u16*)(ws + 27262976L);
  u16* BT  = (u16*)(ws + 190840832L);
  u16* ABF = (u16*)(ws + 193986560L);
  u16* WBF = (u16*)(ws + 195559424L);

  // P1: A^T + A -> bf16
  prep_A<<<dim3(16, 16, 3), 256, 0, stream>>>(s0, s1, s2, BT, ABF);
  // P3: W -> bf16
  prep_W<<<dim3(56), 256, 0, stream>>>(W, WBF);
  // P2: Bt[2s+1] = (A_s^2)^T = Bt[2s] (NT) ABF[s]
  gemm512<<<dim3(4, 4, 3), 256, 0, stream>>>(BT, ABF, BT + SZA,
                                             2L * SZA, 1L * SZA, 2L * SZA);
  // T: x -> Xt bf16
  transpose_x<<<dim3(NB * NC), 256, 0, stream>>>(x, XT);
  // G1: Y[p] = Xt (NT) Bt[p], p = 0..5   (M=26624=208*128, N=512, K=512)
  gemm512<<<dim3(4, 208, 6), 256, 0, stream>>>(XT, BT, Y,
                                               0L, 1L * SZA, MSZ);
  // G2: channel projection + bias -> out
  proj_out<<<dim3(16, NB), 256, 0, stream>>>(XT, WBF, b, out);
}

// Round 2
// 351.644 us; speedup vs baseline: 1.1202x; 1.1202x over previous
//
#include <hip/hip_runtime.h>

// Graph WaveNet GCN on gfx950, bf16 MFMA pipeline.
// out[n,o,w,l] = b[o] + sum_{blk,c} W[o,blk*32+c] * H_blk[n,c,w,l]
//   H_0 = x,  H_{1+p} = x @ P_p over v,  P = [A0, A0^2, A1, A1^2, A2, A2^2]
//
// ws layout (bytes):
//   XT   @ 0          : Xt[(b*32+c)*13+l][v] bf16, 26624x512   (= block 0 of H)
//   Y    @ 27262976   : Y[p][m][w] bf16, 6 x 26624x512          (blocks 1..6)
//   BT   @ 190840832  : Bt[p][w][v] bf16  (P_p^T, NT-GEMM B operand), 6 x 512x512
//   ABF  @ 193986560  : A_s bf16 row-major (B operand for squaring GEMM), 3 x 512x512
//   WBF  @ 195559424  : W bf16 [64][224]

typedef unsigned short u16;
typedef unsigned int   u32;
typedef __bf16 bf16x8 __attribute__((ext_vector_type(8)));
typedef float  f32x4  __attribute__((ext_vector_type(4)));

#define DEVI static __device__ __forceinline__

#define NB   64
#define NC   32
#define NV   512
#define NL   13
#define CO   64
#define CCAT 224
#define SZA   262144L        // 512*512
#define MSZ   (26624L * 512L)

DEVI u16 f2bf(float f) {
  union { float f; u32 u; } v; v.f = f;
  u32 u = v.u;
  return (u16)((u + 0x7fffu + ((u >> 16) & 1u)) >> 16);  // RNE
}

DEVI void gl2lds16(const void* g, void* l) {
  __builtin_amdgcn_global_load_lds((__attribute__((address_space(1))) void*)g,
                                   (__attribute__((address_space(3))) void*)l, 16, 0, 0);
}

// ---------------------------------------------------------------- prep: supports
__global__ __launch_bounds__(256) void prep_A(const float* __restrict__ A0,
                                              const float* __restrict__ A1,
                                              const float* __restrict__ A2,
                                              u16* __restrict__ BT,
                                              u16* __restrict__ ABF) {
  const int s = blockIdx.z;
  const float* A = (s == 0) ? A0 : ((s == 1) ? A1 : A2);
  u16* abf = ABF + (long)s * SZA;
  u16* bt  = BT + (long)(2 * s) * SZA;
  __shared__ float t[32][33];
  const int v0 = blockIdx.x * 32, w0 = blockIdx.y * 32;
  const int tid = threadIdx.x;
  for (int i = tid; i < 1024; i += 256) {
    const int r = i >> 5, c = i & 31;
    const float val = A[(long)(v0 + r) * 512 + w0 + c];
    t[r][c] = val;
    abf[(long)(v0 + r) * 512 + w0 + c] = f2bf(val);
  }
  __syncthreads();
  for (int i = tid; i < 1024; i += 256) {
    const int r = i >> 5, c = i & 31;
    bt[(long)(w0 + r) * 512 + v0 + c] = f2bf(t[c][r]);
  }
}

// ---------------------------------------------------------------- prep: W -> bf16
__global__ __launch_bounds__(256) void prep_W(const float* __restrict__ W,
                                              u16* __restrict__ WBF) {
  const int i = blockIdx.x * 256 + threadIdx.x;
  WBF[i] = f2bf(W[i]);
}

// ---------------------------------------------------------------- transpose x
// x[b][c][v][l] fp32 -> Xt[(b*32+c)*13+l][v] bf16. One block per (b,c).
__global__ __launch_bounds__(256) void transpose_x(const float* __restrict__ x,
                                                   u16* __restrict__ XT) {
  __shared__ __align__(16) float tile[NV * NL];  // 26.6 KB
  const int bc = blockIdx.x;
  const float4* src4 = (const float4*)(x + (long)bc * (NV * NL));
  float4* t4 = (float4*)tile;
  for (int i = threadIdx.x; i < (NV * NL) / 4; i += 256) t4[i] = src4[i];
  __syncthreads();
  u16* dst = XT + (long)bc * (NL * NV);
  for (int j = threadIdx.x; j < NL * 256; j += 256) {
    const int l = j >> 8, v = (j & 255) * 2;   // two adjacent v per thread
    const u32 lo = f2bf(tile[v * NL + l]);
    const u32 hi = f2bf(tile[(v + 1) * NL + l]);
    *(u32*)&dst[l * 512 + v] = lo | (hi << 16);
  }
}

// ---------------------------------------------------------------- small NT GEMM (P2)
__global__ __launch_bounds__(256) void gemm512(const u16* __restrict__ Ag,
                                               const u16* __restrict__ Bg,
                                               u16* __restrict__ Cg,
                                               long aZ, long bZ, long cZ) {
  __shared__ u16 As[128 * 32];
  __shared__ u16 Bs[128 * 32];
  const int p = blockIdx.z;
  const u16* A = Ag + (long)p * aZ;
  const u16* B = Bg + (long)p * bZ;
  u16*       C = Cg + (long)p * cZ;
  const int m0 = blockIdx.y * 128, n0 = blockIdx.x * 128;
  const int tid = threadIdx.x;
  const int lane = tid & 63, wid = tid >> 6;
  const int wm = wid >> 1, wn = wid & 1;
  const int lr = lane & 15, lq = lane >> 4;
  const int srow = lane >> 2, skq = lane & 3;

  f32x4 acc[4][4] = {};

  for (int kt = 0; kt < 16; ++kt) {
    const int k0 = kt * 32;
    __syncthreads();
#pragma unroll
    for (int j = 0; j < 2; ++j) {
      const int rb = wid * 32 + j * 16;
      gl2lds16(A + (long)(m0 + rb + srow) * 512 + (k0 + skq * 8), &As[rb * 32]);
      gl2lds16(B + (long)(n0 + rb + srow) * 512 + (k0 + skq * 8), &Bs[rb * 32]);
    }
    __syncthreads();
    bf16x8 af[4], bv[4];
#pragma unroll
    for (int t = 0; t < 4; ++t) {
      af[t] = *(const bf16x8*)&As[(wm * 64 + t * 16 + lr) * 32 + lq * 8];
      bv[t] = *(const bf16x8*)&Bs[(wn * 64 + t * 16 + lr) * 32 + lq * 8];
    }
#pragma unroll
    for (int i = 0; i < 4; ++i)
#pragma unroll
      for (int j = 0; j < 4; ++j)
        acc[i][j] = __builtin_amdgcn_mfma_f32_16x16x32_bf16(af[i], bv[j], acc[i][j], 0, 0, 0);
  }
#pragma unroll
  for (int i = 0; i < 4; ++i) {
    const int mr = m0 + wm * 64 + i * 16 + lq * 4;
#pragma unroll
    for (int j = 0; j < 4; ++j) {
      const int nc = n0 + wn * 64 + j * 16 + lr;
#pragma unroll
      for (int r = 0; r < 4; ++r)
        C[(long)(mr + r) * 512 + nc] = f2bf(acc[i][j][r]);
    }
  }
}

// ---------------------------------------------------------------- big NT GEMM (G1)
// grid (24, 208): blockIdx.x = p*4 + n_tile (p-fastest varies within 24-group so
// consecutive blocks share the A row-panel; all six B matrices stay L2-resident).
__global__ __launch_bounds__(256) void gemm_big(const u16* __restrict__ A,
                                                const u16* __restrict__ Bg,
                                                u16* __restrict__ Cg) {
  __shared__ u16 As[128 * 32];
  __shared__ u16 Bs[128 * 32];
  const int p = blockIdx.x >> 2;
  const int n0 = (blockIdx.x & 3) * 128;
  const int m0 = blockIdx.y * 128;
  const u16* B = Bg + (long)p * SZA;
  u16*       C = Cg + (long)p * MSZ;
  const int tid = threadIdx.x;
  const int lane = tid & 63, wid = tid >> 6;
  const int wm = wid >> 1, wn = wid & 1;
  const int lr = lane & 15, lq = lane >> 4;
  const int srow = lane >> 2, skq = lane & 3;

  f32x4 acc[4][4] = {};

  for (int kt = 0; kt < 16; ++kt) {
    const int k0 = kt * 32;
    __syncthreads();
#pragma unroll
    for (int j = 0; j < 2; ++j) {
      const int rb = wid * 32 + j * 16;
      gl2lds16(A + (long)(m0 + rb + srow) * 512 + (k0 + skq * 8), &As[rb * 32]);
      gl2lds16(B + (long)(n0 + rb + srow) * 512 + (k0 + skq * 8), &Bs[rb * 32]);
    }
    __syncthreads();
    bf16x8 af[4], bv[4];
#pragma unroll
    for (int t = 0; t < 4; ++t) {
      af[t] = *(const bf16x8*)&As[(wm * 64 + t * 16 + lr) * 32 + lq * 8];
      bv[t] = *(const bf16x8*)&Bs[(wn * 64 + t * 16 + lr) * 32 + lq * 8];
    }
#pragma unroll
    for (int i = 0; i < 4; ++i)
#pragma unroll
      for (int j = 0; j < 4; ++j)
        acc[i][j] = __builtin_amdgcn_mfma_f32_16x16x32_bf16(af[i], bv[j], acc[i][j], 0, 0, 0);
  }
#pragma unroll
  for (int i = 0; i < 4; ++i) {
    const int mr = m0 + wm * 64 + i * 16 + lq * 4;
#pragma unroll
    for (int j = 0; j < 4; ++j) {
      const int nc = n0 + wn * 64 + j * 16 + lr;
#pragma unroll
      for (int r = 0; r < 4; ++r)
        C[(long)(mr + r) * 512 + nc] = f2bf(acc[i][j][r]);
    }
  }
}

// ---------------------------------------------------------------- channel projection
// Block: n = blockIdx.y, w-chunk (32 w's) = blockIdx.x. 512 threads, 8 waves:
// wave = (th = wid>>2) x (og = wid&3); og -> 16 output rows, th -> 16 w-tiles.
// acc per thread: 16 f32x4 (64 VGPRs).
// Staging: thread (c = tid>>4, q = tid&15); ushort4 load = (1 c, 1 lp, 4 w);
// LDS col-chunk XOR-swizzled by (w>>2)&3 to cut write bank conflicts.
__global__ __launch_bounds__(512) void proj_out(const u16* __restrict__ Yall, // [7][26624][512]
                                                const u16* __restrict__ WBF,  // [64][224]
                                                const float* __restrict__ bias,
                                                float* __restrict__ out) {
  __shared__ u16 Hs[512 * 32];  // 32 KB; row = w*16+lp (64 B), col = swizzled c
  const int n = blockIdx.y, wch = blockIdx.x;
  const int w_base = wch * 32;
  const int tid = threadIdx.x;
  const int lane = tid & 63, wid = tid >> 6;
  const int og = wid & 3, th = wid >> 2;
  const int lr = lane & 15, lq = lane >> 4;
  const int c = tid >> 4, q = tid & 15;

  f32x4 acc[16] = {};
  float bia[4];
#pragma unroll
  for (int r = 0; r < 4; ++r) bia[r] = bias[og * 16 + lq * 4 + r];

  const int cchunk = c >> 3, cin = c & 7;

  for (int blk = 0; blk < 7; ++blk) {
    const u16* Yrow = Yall + (long)blk * MSZ + ((long)(n * NC + c) * NL) * 512 + w_base;
    __syncthreads();
    for (int i = q; i < 104; i += 16) {       // 104 = 13 lp * 8 w-quads
      const int lp = i >> 3, w4 = i & 7;
      const ushort4 d = *(const ushort4*)(Yrow + lp * 512 + w4 * 4);
      const int colc = ((cchunk ^ (w4 & 3)) << 3) | cin;
      const int rbase = (w4 * 4) * 16 + lp;
      Hs[(rbase +  0) * 32 + colc] = d.x;
      Hs[(rbase + 16) * 32 + colc] = d.y;
      Hs[(rbase + 32) * 32 + colc] = d.z;
      Hs[(rbase + 48) * 32 + colc] = d.w;
    }
    __syncthreads();
    const bf16x8 af = *(const bf16x8*)&WBF[(og * 16 + lr) * CCAT + blk * 32 + lq * 8];
#pragma unroll
    for (int tt = 0; tt < 16; ++tt) {
      const int t = th * 16 + tt;            // w-tile index; w = w_base + t
      const bf16x8 bv = *(const bf16x8*)&Hs[(t * 16 + lr) * 32 + ((lq ^ ((t >> 2) & 3)) << 3)];
      acc[tt] = __builtin_amdgcn_mfma_f32_16x16x32_bf16(af, bv, acc[tt], 0, 0, 0);
    }
  }
  if (lr < NL) {
#pragma unroll
    for (int tt = 0; tt < 16; ++tt) {
      const int w = w_base + th * 16 + tt;
      const long base = (((long)n * CO + og * 16 + lq * 4) * 512 + w) * NL + lr;
#pragma unroll
      for (int r = 0; r < 4; ++r)
        out[base + (long)r * (512 * NL)] = acc[tt][r] + bia[r];
    }
  }
}

extern "C" void kernel_launch(void* const* d_in, const int* in_sizes, int n_in,
                              void* d_out, int out_size, void* d_ws, size_t ws_size,
                              hipStream_t stream) {
  const float* x  = (const float*)d_in[0];
  const float* s0 = (const float*)d_in[1];
  const float* s1 = (const float*)d_in[2];
  const float* s2 = (const float*)d_in[3];
  const float* W  = (const float*)d_in[4];
  const float* b  = (const float*)d_in[5];
  float* out = (float*)d_out;

  char* ws = (char*)d_ws;
  u16* XT  = (u16*)(ws);                 // also serves as Yall block 0
  u16* Y   = (u16*)(ws + 27262976L);
  u16* BT  = (u16*)(ws + 190840832L);
  u16* ABF = (u16*)(ws + 193986560L);
  u16* WBF = (u16*)(ws + 195559424L);

  prep_A<<<dim3(16, 16, 3), 256, 0, stream>>>(s0, s1, s2, BT, ABF);
  prep_W<<<dim3(56), 256, 0, stream>>>(W, WBF);
  // Bt[2s+1] = (A_s^2)^T = Bt[2s] (NT) ABF[s]
  gemm512<<<dim3(4, 4, 3), 256, 0, stream>>>(BT, ABF, BT + SZA,
                                             2L * SZA, 1L * SZA, 2L * SZA);
  transpose_x<<<dim3(NB * NC), 256, 0, stream>>>(x, XT);
  // G1: Y[p] = Xt (NT) Bt[p]; grid x = p*4 + n_tile (A-panel shared by 24 consecutive blocks)
  gemm_big<<<dim3(24, 208), 256, 0, stream>>>(XT, BT, Y);
  proj_out<<<dim3(16, NB), 512, 0, stream>>>(XT, WBF, b, out);
}